// Round 8
// baseline (103.273 us; speedup 1.0000x reference)
//
#include <hip/hip_runtime.h>

#define NB 8
#define NP 131072
#define NM 16
#define THRESH 0.5f
#define BLK 256
#define BPB (NP / BLK)           // 512 match blocks per batch (PPT=1)
#define MATCH_BLOCKS (NB * BPB)  // 4096
#define FOCAL_BLOCKS 128         // streaming-baseline blocks
#define NBLOCKS (MATCH_BLOCKS + FOCAL_BLOCKS)   // 4224
#define NPAIR (NB * NM)          // 128

typedef unsigned long long u64;
typedef unsigned int u32;

// ---------- DPP wave-64 reductions ----------
// row_shr 1,2,4,8 then row_bcast:15, row_bcast:31; lane 63 holds the result.
// old=0 fill is harmless for sum (adds 0) and max of non-negatives.

template <int CTRL>
__device__ __forceinline__ float dppmv(float x) {
    return __int_as_float(__builtin_amdgcn_update_dpp(
        0, __float_as_int(x), CTRL, 0xf, 0xf, false));
}

__device__ __forceinline__ float wave_max63(float x) {   // x >= 0 required
    x = fmaxf(x, dppmv<0x111>(x));
    x = fmaxf(x, dppmv<0x112>(x));
    x = fmaxf(x, dppmv<0x114>(x));
    x = fmaxf(x, dppmv<0x118>(x));
    x = fmaxf(x, dppmv<0x142>(x));
    x = fmaxf(x, dppmv<0x143>(x));
    return x;
}

__device__ __forceinline__ float wave_sum63(float x) {
    x += dppmv<0x111>(x);
    x += dppmv<0x112>(x);
    x += dppmv<0x114>(x);
    x += dppmv<0x118>(x);
    x += dppmv<0x142>(x);
    x += dppmv<0x143>(x);
    return x;
}

__device__ __forceinline__ float bcast63(float x) {
    return __int_as_float(__builtin_amdgcn_readlane(__float_as_int(x), 63));
}

// ---------- shared math (identical formulas everywhere) ----------

__device__ __forceinline__ float iou_term(float inter, float va, float vb) {
    return (inter > 0.0f) ? inter * __builtin_amdgcn_rcpf(va + vb - inter) : 0.0f;
}

__device__ __forceinline__ float focal_term(float x, bool pos) {
    float t = __expf(-fabsf(x));                 // e^{-|x|}
    float r = __builtin_amdgcn_rcpf(1.0f + t);   // 1/(1+t)
    float L = __logf(1.0f + t);                  // log1p(e^{-|x|})
    float ce = (pos ? fmaxf(-x, 0.0f) : fmaxf(x, 0.0f)) + L;   // softplus
    float omp = (pos == (x >= 0.0f)) ? t * r : r;              // 1 - pt
    float w = pos ? 0.25f : 0.75f;
    return w * omp * omp * ce;
}

__device__ __forceinline__ float l1_enc(const float* lp,
                                        const float blo[3], const float bhi[3],
                                        const float pc[3], const float ps[3]) {
    float s = 0.0f;
#pragma unroll
    for (int k = 0; k < 3; ++k) {
        float gc = (blo[k] + bhi[k]) / 2.0f;
        float gs = bhi[k] - blo[k];
        float e  = (gc - pc[k]) / (ps[k] / 10.0f);
        float e2 = __logf(gs / ps[k]) * 5.0f;
        s += fabsf(lp[k]     - e);
        s += fabsf(lp[3 + k] - e2);
    }
    return s;
}

__device__ __forceinline__ u32 decode_p(u64 k) { return ~(u32)(k & 0xFFFFFFFFull); }

// ---------- kernel 1: match role (PPT=1) + focal-baseline role ----------

__global__ __launch_bounds__(BLK, 8) void main_kernel(
        const float* __restrict__ locs, const float* __restrict__ scores,
        const float* __restrict__ boxes, const int* __restrict__ labels,
        const float* __restrict__ priors,
        u64* __restrict__ keys_out,              // [NPAIR][BPB], fully written
        float4* __restrict__ part) {             // [NBLOCKS]
    __shared__ float4 s_box[NM][2];              // {lo0,lo1,lo2,hi0} {hi1,hi2,va,lab}
    __shared__ u64    s_wkey[4][NM];
    __shared__ float  s_wred[4][3];

    const int tid  = threadIdx.x;
    const int bid  = blockIdx.x;
    const int lane = tid & 63, wave = tid >> 6;

    // ===== focal-baseline role: sum focal(x, 0) over all (b,p) =====
    if (bid >= MATCH_BLOCKS) {
        const int fblk = bid - MATCH_BLOCKS;
        const float4* sc4 = reinterpret_cast<const float4*>(scores);
        // scores: 2M floats = 524288 float4; 4096 per block, 16 per thread
        float f = 0.0f;
#pragma unroll
        for (int i = 0; i < 16; ++i) {
            float4 v = sc4[(size_t)fblk * 4096 + i * BLK + tid];
            f += focal_term(v.y, false) + focal_term(v.w, false);
        }
        f = wave_sum63(f);
        if (lane == 63) s_wred[wave][0] = f;
        __syncthreads();
        if (tid == 0)
            part[bid] = make_float4(s_wred[0][0] + s_wred[1][0] +
                                    s_wred[2][0] + s_wred[3][0], 0.0f, 0.0f, 0.0f);
        return;
    }

    // ===== match role: one prior per thread =====
    const int b    = bid >> 9;                   // bid / BPB
    const int xblk = bid & (BPB - 1);
    const int p    = (xblk << 8) | tid;
    const int pbase = (xblk << 8) | (wave << 6);

    if (tid < NM) {
        const float* bx = &boxes[(b * NM + tid) * 6];
        float l0 = bx[0], l1 = bx[1], l2 = bx[2];
        float h0 = bx[3], h1 = bx[4], h2 = bx[5];
        s_box[tid][0] = make_float4(l0, l1, l2, h0);
        float va = (h0 - l0) * (h1 - l1) * (h2 - l2);
        s_box[tid][1] = make_float4(h1, h2, va, __int_as_float(labels[b * NM + tid]));
    }
    __syncthreads();

    // prior: 3 aligned float2 loads; mirror reference op order
    const float2* pr2 = reinterpret_cast<const float2*>(priors);
    float2 q0 = pr2[(size_t)p * 3 + 0], q1 = pr2[(size_t)p * 3 + 1], q2 = pr2[(size_t)p * 3 + 2];
    const float pc[3] = {q0.x, q0.y, q1.x};
    const float ps[3] = {q1.y, q2.x, q2.y};
    float pl[3], ph[3];
#pragma unroll
    for (int k = 0; k < 3; ++k) { pl[k] = pc[k] - ps[k] / 2.0f; ph[k] = pc[k] + ps[k] / 2.0f; }
    const float vb = (ph[0] - pl[0]) * (ph[1] - pl[1]) * (ph[2] - pl[2]);

    // phase 1: all 16 IoUs into registers (max ILP); first-max tracking
    float ci[NM];
    float best = -1.0f; int bm = 0;
#pragma unroll
    for (int m = 0; m < NM; ++m) {
        float4 A = s_box[m][0], B4 = s_box[m][1];
        float d0 = fminf(A.w,  ph[0]) - fmaxf(A.x, pl[0]);
        float d1 = fminf(B4.x, ph[1]) - fmaxf(A.y, pl[1]);
        float d2 = fminf(B4.y, ph[2]) - fmaxf(A.z, pl[2]);
        float inter = fmaxf(d0, 0.0f) * fmaxf(d1, 0.0f) * fmaxf(d2, 0.0f);
        ci[m] = iou_term(inter, B4.z, vb);
        if (ci[m] > best) { best = ci[m]; bm = m; }      // strict > = first max
    }

    // phase 2: 16 independent wave-max chains; lane IS the prior (PPT=1)
#pragma unroll
    for (int m = 0; m < NM; ++m) {
        float wm = bcast63(wave_max63(ci[m]));
        u64 eq = __ballot(ci[m] == wm);
        int ls = __ffsll(eq) - 1;                        // lowest lane = lowest p
        if (lane == 0)
            s_wkey[wave][m] = ((u64)__float_as_uint(wm) << 32)
                            | (u32)~(u32)(pbase + ls);
    }

    // epilogue: delta-focal + loc, only under the rare positive mask
    float4 Bb = s_box[bm][1];
    const bool pos = (best >= THRESH) && (__float_as_int(Bb.w) > 0);
    float f = 0.0f, l = 0.0f, n = 0.0f;
    if (pos) {
        const float x = scores[((size_t)b * NP + p) * 2 + 1];
        f = focal_term(x, true) - focal_term(x, false);  // delta vs baseline
        float4 Ab = s_box[bm][0];
        float blo[3] = {Ab.x, Ab.y, Ab.z}, bhi[3] = {Ab.w, Bb.x, Bb.y};
        l = l1_enc(&locs[((size_t)b * NP + p) * 6], blo, bhi, pc, ps);
        n = 1.0f;
    }

    f = wave_sum63(f); l = wave_sum63(l); n = wave_sum63(n);
    if (lane == 63) { s_wred[wave][0] = f; s_wred[wave][1] = l; s_wred[wave][2] = n; }
    __syncthreads();

    if (tid < NM) {
        u64 k = s_wkey[0][tid];
#pragma unroll
        for (int w = 1; w < 4; ++w) k = (s_wkey[w][tid] > k) ? s_wkey[w][tid] : k;
        keys_out[(size_t)(b * NM + tid) * BPB + xblk] = k;
    }
    if (tid == 0) {
        part[bid] = make_float4(s_wred[0][0] + s_wred[1][0] + s_wred[2][0] + s_wred[3][0],
                                s_wred[0][1] + s_wred[1][1] + s_wred[2][1] + s_wred[3][1],
                                s_wred[0][2] + s_wred[1][2] + s_wred[2][2] + s_wred[3][2],
                                0.0f);
    }
}

// ---------- kernel 2: key reduce + partial reduce + override fixups + finalize ----------

__global__ __launch_bounds__(1024) void finalize_kernel(
        const float* __restrict__ locs, const float* __restrict__ scores,
        const float* __restrict__ boxes, const int* __restrict__ labels,
        const float* __restrict__ priors, const u64* __restrict__ keys_in,
        const float4* __restrict__ part, float* __restrict__ out) {
    __shared__ u64   s_key[NPAIR];
    __shared__ float s_red[16][3];
    __shared__ float s_fix[16][3];
    const int t = threadIdx.x, lane = t & 63, wave = t >> 6;   // 16 waves

    // 1) reduce per-block partials (match f/l/n + focal baselines)
    float f = 0.0f, l = 0.0f, n = 0.0f;
    for (int i = t; i < NBLOCKS; i += 1024) {
        float4 v = part[i]; f += v.x; l += v.y; n += v.z;
    }
    f = wave_sum63(f); l = wave_sum63(l); n = wave_sum63(n);
    if (lane == 63) { s_red[wave][0] = f; s_red[wave][1] = l; s_red[wave][2] = n; }

    // 2) global key max per (b,m): one wave per 8 pairs
#pragma unroll
    for (int i = 0; i < 8; ++i) {
        const int pair = wave * 8 + i;
        const u64* kp = keys_in + (size_t)pair * BPB;
        u64 k = 0;
#pragma unroll
        for (int j = 0; j < BPB / 64; ++j) {     // 8 coalesced loads per lane
            u64 v = kp[j * 64 + lane];
            k = (v > k) ? v : k;
        }
#pragma unroll
        for (int off = 32; off > 0; off >>= 1) {
            u64 o = __shfl_down(k, off);
            k = (o > k) ? o : k;
        }
        if (lane == 0) s_key[pair] = k;
    }
    __syncthreads();

    // 3) per-(b,m) override fixup (delta form matches the split-focal sum)
    float df = 0.0f, dl = 0.0f, dn = 0.0f;
    if (t < NPAIR) {
        const int b = t / NM, m = t % NM;
        const u32 pstar = decode_p(s_key[t]);
        bool skip = false;                        // duplicate prior: last m wins
        for (int mm = m + 1; mm < NM; ++mm)
            skip |= (decode_p(s_key[b * NM + mm]) == pstar);
        if (!skip) {
            const int p = (int)pstar;
            float pc[3], ps[3], pl[3], ph[3];
#pragma unroll
            for (int k = 0; k < 3; ++k) { pc[k] = priors[p * 6 + k]; ps[k] = priors[p * 6 + 3 + k]; }
#pragma unroll
            for (int k = 0; k < 3; ++k) { pl[k] = pc[k] - ps[k] / 2.0f; ph[k] = pc[k] + ps[k] / 2.0f; }
            const float vb = (ph[0] - pl[0]) * (ph[1] - pl[1]) * (ph[2] - pl[2]);

            // recompute this prior's original best match (bit-identical math)
            float best = -1.0f; int bestm = 0;
            for (int mm = 0; mm < NM; ++mm) {
                const float* bx = &boxes[(b * NM + mm) * 6];
                float d0 = fminf(bx[3], ph[0]) - fmaxf(bx[0], pl[0]);
                float d1 = fminf(bx[4], ph[1]) - fmaxf(bx[1], pl[1]);
                float d2 = fminf(bx[5], ph[2]) - fmaxf(bx[2], pl[2]);
                float inter = fmaxf(d0, 0.0f) * fmaxf(d1, 0.0f) * fmaxf(d2, 0.0f);
                float va = (bx[3] - bx[0]) * (bx[4] - bx[1]) * (bx[5] - bx[2]);
                float iou = iou_term(inter, va, vb);
                if (iou > best) { best = iou; bestm = mm; }
            }
            const bool old_pos = (best >= THRESH) && (labels[b * NM + bestm] > 0);
            const bool new_pos = (labels[b * NM + m] > 0);   // overlap forced to 1.0

            const float x = scores[((size_t)b * NP + p) * 2 + 1];
            df = focal_term(x, new_pos) - focal_term(x, old_pos);
            dn = (new_pos ? 1.0f : 0.0f) - (old_pos ? 1.0f : 0.0f);

            const float* lp = &locs[((size_t)b * NP + p) * 6];
            if (new_pos) {
                const float* bx = &boxes[(b * NM + m) * 6];
                float blo[3] = {bx[0], bx[1], bx[2]}, bhi[3] = {bx[3], bx[4], bx[5]};
                dl += l1_enc(lp, blo, bhi, pc, ps);
            }
            if (old_pos) {
                const float* bx = &boxes[(b * NM + bestm) * 6];
                float blo[3] = {bx[0], bx[1], bx[2]}, bhi[3] = {bx[3], bx[4], bx[5]};
                dl -= l1_enc(lp, blo, bhi, pc, ps);
            }
        }
    }
    df = wave_sum63(df); dl = wave_sum63(dl); dn = wave_sum63(dn);
    if (lane == 63) { s_fix[wave][0] = df; s_fix[wave][1] = dl; s_fix[wave][2] = dn; }
    __syncthreads();

    // 4) finalize (single thread, fixed order)
    if (t == 0) {
        float tf = 0.0f, tl = 0.0f, tn = 0.0f;
        for (int w = 0; w < 16; ++w) {
            tf += s_red[w][0] + s_fix[w][0];
            tl += s_red[w][1] + s_fix[w][1];
            tn += s_red[w][2] + s_fix[w][2];
        }
        out[0] = tf / (float)(NB * NP);                                   // conf_loss
        out[1] = (tn > 0.5f) ? tl / fmaxf(tn * 6.0f, 1.0f) : 0.0f;        // loc_loss
    }
}

// ---------- launch (2 dispatches, no memset, no atomics) ----------

extern "C" void kernel_launch(void* const* d_in, const int* in_sizes, int n_in,
                              void* d_out, int out_size, void* d_ws, size_t ws_size,
                              hipStream_t stream) {
    const float* locs   = (const float*)d_in[0];
    const float* scores = (const float*)d_in[1];
    const float* boxes  = (const float*)d_in[2];
    const int*   labels = (const int*)d_in[3];
    const float* priors = (const float*)d_in[4];
    float* out = (float*)d_out;

    u64*    keys = (u64*)d_ws;                                        // 512 KB
    float4* part = (float4*)((char*)d_ws + (size_t)NPAIR * BPB * 8);  // 68 KB

    main_kernel<<<NBLOCKS, BLK, 0, stream>>>(locs, scores, boxes, labels, priors,
                                             keys, part);
    finalize_kernel<<<1, 1024, 0, stream>>>(locs, scores, boxes, labels, priors, keys,
                                            part, out);
}

// Round 9
// 42.917 us; speedup vs baseline: 2.4063x; 2.4063x over previous
//
#include <hip/hip_runtime.h>

#define NB 8
#define NP 131072
#define NM 16
#define THRESH 0.5f
#define BLK 256
#define BPB (NP / BLK)           // 512 match blocks per batch (PPT=1)
#define MATCH_BLOCKS (NB * BPB)  // 4096
#define FOCAL_BLOCKS 128         // streaming-baseline blocks
#define NBLOCKS (MATCH_BLOCKS + FOCAL_BLOCKS)   // 4224
#define NPAIR (NB * NM)          // 128

typedef unsigned long long u64;
typedef unsigned int u32;

// ---------- DPP wave-64 reductions ----------
// row_shr 1,2,4,8 then row_bcast:15, row_bcast:31; lane 63 holds the result.
// old=0 fill is harmless for sum (adds 0) and max of non-negatives.

template <int CTRL>
__device__ __forceinline__ float dppmv(float x) {
    return __int_as_float(__builtin_amdgcn_update_dpp(
        0, __float_as_int(x), CTRL, 0xf, 0xf, false));
}

__device__ __forceinline__ float wave_max63(float x) {   // x >= 0 required
    x = fmaxf(x, dppmv<0x111>(x));
    x = fmaxf(x, dppmv<0x112>(x));
    x = fmaxf(x, dppmv<0x114>(x));
    x = fmaxf(x, dppmv<0x118>(x));
    x = fmaxf(x, dppmv<0x142>(x));
    x = fmaxf(x, dppmv<0x143>(x));
    return x;
}

__device__ __forceinline__ float wave_sum63(float x) {
    x += dppmv<0x111>(x);
    x += dppmv<0x112>(x);
    x += dppmv<0x114>(x);
    x += dppmv<0x118>(x);
    x += dppmv<0x142>(x);
    x += dppmv<0x143>(x);
    return x;
}

__device__ __forceinline__ float bcast63(float x) {
    return __int_as_float(__builtin_amdgcn_readlane(__float_as_int(x), 63));
}

// ---------- shared math (identical formulas everywhere) ----------

__device__ __forceinline__ float iou_term(float inter, float va, float vb) {
    return (inter > 0.0f) ? inter * __builtin_amdgcn_rcpf(va + vb - inter) : 0.0f;
}

__device__ __forceinline__ float focal_term(float x, bool pos) {
    float t = __expf(-fabsf(x));                 // e^{-|x|}
    float r = __builtin_amdgcn_rcpf(1.0f + t);   // 1/(1+t)
    float L = __logf(1.0f + t);                  // log1p(e^{-|x|})
    float ce = (pos ? fmaxf(-x, 0.0f) : fmaxf(x, 0.0f)) + L;   // softplus
    float omp = (pos == (x >= 0.0f)) ? t * r : r;              // 1 - pt
    float w = pos ? 0.25f : 0.75f;
    return w * omp * omp * ce;
}

__device__ __forceinline__ float l1_enc(const float* lp,
                                        const float blo[3], const float bhi[3],
                                        const float pc[3], const float ps[3]) {
    float s = 0.0f;
#pragma unroll
    for (int k = 0; k < 3; ++k) {
        float gc = (blo[k] + bhi[k]) / 2.0f;
        float gs = bhi[k] - blo[k];
        float e  = (gc - pc[k]) / (ps[k] / 10.0f);
        float e2 = __logf(gs / ps[k]) * 5.0f;
        s += fabsf(lp[k]     - e);
        s += fabsf(lp[3 + k] - e2);
    }
    return s;
}

__device__ __forceinline__ u32 decode_p(u64 k) { return ~(u32)(k & 0xFFFFFFFFull); }

// ---------- kernel 1: match role (PPT=1, lean regs) + focal-baseline role ----------

__global__ __launch_bounds__(BLK) void main_kernel(
        const float* __restrict__ locs, const float* __restrict__ scores,
        const float* __restrict__ boxes, const int* __restrict__ labels,
        const float* __restrict__ priors,
        u64* __restrict__ keys_out,              // [NPAIR][BPB], fully written
        float4* __restrict__ part) {             // [NBLOCKS]
    __shared__ float4 s_box[NM][2];              // {lo0,lo1,lo2,hi0} {hi1,hi2,va,lab}
    __shared__ u64    s_wkey[4][NM];
    __shared__ float  s_wred[4][3];

    const int tid  = threadIdx.x;
    const int bid  = blockIdx.x;
    const int lane = tid & 63, wave = tid >> 6;

    // ===== focal-baseline role: sum focal(x, 0) over all (b,p) =====
    if (bid >= MATCH_BLOCKS) {
        const int fblk = bid - MATCH_BLOCKS;
        const float4* sc4 = reinterpret_cast<const float4*>(scores);
        // scores: 2M floats = 524288 float4; 4096 per block, 16 per thread
        float f = 0.0f;
#pragma unroll
        for (int i = 0; i < 16; ++i) {
            float4 v = sc4[(size_t)fblk * 4096 + i * BLK + tid];
            f += focal_term(v.y, false) + focal_term(v.w, false);
        }
        f = wave_sum63(f);
        if (lane == 63) s_wred[wave][0] = f;
        __syncthreads();
        if (tid == 0)
            part[bid] = make_float4(s_wred[0][0] + s_wred[1][0] +
                                    s_wred[2][0] + s_wred[3][0], 0.0f, 0.0f, 0.0f);
        return;
    }

    // ===== match role: one prior per thread =====
    const int b    = bid >> 9;                   // bid / BPB
    const int xblk = bid & (BPB - 1);
    const int p    = (xblk << 8) | tid;
    const int pbase = (xblk << 8) | (wave << 6);

    if (tid < NM) {
        const float* bx = &boxes[(b * NM + tid) * 6];
        float l0 = bx[0], l1 = bx[1], l2 = bx[2];
        float h0 = bx[3], h1 = bx[4], h2 = bx[5];
        s_box[tid][0] = make_float4(l0, l1, l2, h0);
        float va = (h0 - l0) * (h1 - l1) * (h2 - l2);
        s_box[tid][1] = make_float4(h1, h2, va, __int_as_float(labels[b * NM + tid]));
    }
    __syncthreads();

    // prior: 3 aligned float2 loads; mirror reference op order
    const float2* pr2 = reinterpret_cast<const float2*>(priors);
    float2 q0 = pr2[(size_t)p * 3 + 0], q1 = pr2[(size_t)p * 3 + 1], q2 = pr2[(size_t)p * 3 + 2];
    float pl[3], ph[3];
    {
        const float pcf[3] = {q0.x, q0.y, q1.x};
        const float psf[3] = {q1.y, q2.x, q2.y};
#pragma unroll
        for (int k = 0; k < 3; ++k) {
            pl[k] = pcf[k] - psf[k] / 2.0f;
            ph[k] = pcf[k] + psf[k] / 2.0f;
        }
    }
    const float vb = (ph[0] - pl[0]) * (ph[1] - pl[1]) * (ph[2] - pl[2]);

    // per-m: IoU + in-loop wave reduction (PPT=1: lane IS the prior; no ci[] array)
    float best = -1.0f; int bm = 0;
#pragma unroll
    for (int m = 0; m < NM; ++m) {
        float4 A = s_box[m][0], B4 = s_box[m][1];
        float d0 = fminf(A.w,  ph[0]) - fmaxf(A.x, pl[0]);
        float d1 = fminf(B4.x, ph[1]) - fmaxf(A.y, pl[1]);
        float d2 = fminf(B4.y, ph[2]) - fmaxf(A.z, pl[2]);
        float inter = fmaxf(d0, 0.0f) * fmaxf(d1, 0.0f) * fmaxf(d2, 0.0f);
        float iou = iou_term(inter, B4.z, vb);
        if (iou > best) { best = iou; bm = m; }          // strict > = first max
        float wm = bcast63(wave_max63(iou));
        u64 eq = __ballot(iou == wm);
        int ls = __ffsll(eq) - 1;                        // lowest lane = lowest p
        if (lane == 0)
            s_wkey[wave][m] = ((u64)__float_as_uint(wm) << 32)
                            | (u32)~(u32)(pbase + ls);
    }

    // epilogue: delta-focal + loc, only under the rare positive mask
    float4 Bb = s_box[bm][1];
    const bool pos = (best >= THRESH) && (__float_as_int(Bb.w) > 0);
    float f = 0.0f, l = 0.0f, n = 0.0f;
    if (pos) {
        const float x = scores[((size_t)b * NP + p) * 2 + 1];
        f = focal_term(x, true) - focal_term(x, false);  // delta vs baseline
        float4 Ab = s_box[bm][0];
        float blo[3] = {Ab.x, Ab.y, Ab.z}, bhi[3] = {Ab.w, Bb.x, Bb.y};
        const float pcr[3] = {q0.x, q0.y, q1.x};
        const float psr[3] = {q1.y, q2.x, q2.y};
        l = l1_enc(&locs[((size_t)b * NP + p) * 6], blo, bhi, pcr, psr);
        n = 1.0f;
    }

    f = wave_sum63(f); l = wave_sum63(l); n = wave_sum63(n);
    if (lane == 63) { s_wred[wave][0] = f; s_wred[wave][1] = l; s_wred[wave][2] = n; }
    __syncthreads();

    if (tid < NM) {
        u64 k = s_wkey[0][tid];
#pragma unroll
        for (int w = 1; w < 4; ++w) k = (s_wkey[w][tid] > k) ? s_wkey[w][tid] : k;
        keys_out[(size_t)(b * NM + tid) * BPB + xblk] = k;
    }
    if (tid == 0) {
        part[bid] = make_float4(s_wred[0][0] + s_wred[1][0] + s_wred[2][0] + s_wred[3][0],
                                s_wred[0][1] + s_wred[1][1] + s_wred[2][1] + s_wred[3][1],
                                s_wred[0][2] + s_wred[1][2] + s_wred[2][2] + s_wred[3][2],
                                0.0f);
    }
}

// ---------- kernel 2: key reduce + partial reduce + override fixups + finalize ----------

__global__ __launch_bounds__(1024) void finalize_kernel(
        const float* __restrict__ locs, const float* __restrict__ scores,
        const float* __restrict__ boxes, const int* __restrict__ labels,
        const float* __restrict__ priors, const u64* __restrict__ keys_in,
        const float4* __restrict__ part, float* __restrict__ out) {
    __shared__ u64   s_key[NPAIR];
    __shared__ float s_red[16][3];
    __shared__ float s_fix[16][3];
    const int t = threadIdx.x, lane = t & 63, wave = t >> 6;   // 16 waves

    // 1) reduce per-block partials (match f/l/n + focal baselines)
    float f = 0.0f, l = 0.0f, n = 0.0f;
    for (int i = t; i < NBLOCKS; i += 1024) {
        float4 v = part[i]; f += v.x; l += v.y; n += v.z;
    }
    f = wave_sum63(f); l = wave_sum63(l); n = wave_sum63(n);
    if (lane == 63) { s_red[wave][0] = f; s_red[wave][1] = l; s_red[wave][2] = n; }

    // 2) global key max per (b,m): one wave per 8 pairs
#pragma unroll
    for (int i = 0; i < 8; ++i) {
        const int pair = wave * 8 + i;
        const u64* kp = keys_in + (size_t)pair * BPB;
        u64 k = 0;
#pragma unroll
        for (int j = 0; j < BPB / 64; ++j) {     // 8 coalesced loads per lane
            u64 v = kp[j * 64 + lane];
            k = (v > k) ? v : k;
        }
#pragma unroll
        for (int off = 32; off > 0; off >>= 1) {
            u64 o = __shfl_down(k, off);
            k = (o > k) ? o : k;
        }
        if (lane == 0) s_key[pair] = k;
    }
    __syncthreads();

    // 3) per-(b,m) override fixup (delta form matches the split-focal sum)
    float df = 0.0f, dl = 0.0f, dn = 0.0f;
    if (t < NPAIR) {
        const int b = t / NM, m = t % NM;
        const u32 pstar = decode_p(s_key[t]);
        bool skip = false;                        // duplicate prior: last m wins
        for (int mm = m + 1; mm < NM; ++mm)
            skip |= (decode_p(s_key[b * NM + mm]) == pstar);
        if (!skip) {
            const int p = (int)pstar;
            float pc[3], ps[3], pl[3], ph[3];
#pragma unroll
            for (int k = 0; k < 3; ++k) { pc[k] = priors[p * 6 + k]; ps[k] = priors[p * 6 + 3 + k]; }
#pragma unroll
            for (int k = 0; k < 3; ++k) { pl[k] = pc[k] - ps[k] / 2.0f; ph[k] = pc[k] + ps[k] / 2.0f; }
            const float vb = (ph[0] - pl[0]) * (ph[1] - pl[1]) * (ph[2] - pl[2]);

            // recompute this prior's original best match (bit-identical math)
            float best = -1.0f; int bestm = 0;
            for (int mm = 0; mm < NM; ++mm) {
                const float* bx = &boxes[(b * NM + mm) * 6];
                float d0 = fminf(bx[3], ph[0]) - fmaxf(bx[0], pl[0]);
                float d1 = fminf(bx[4], ph[1]) - fmaxf(bx[1], pl[1]);
                float d2 = fminf(bx[5], ph[2]) - fmaxf(bx[2], pl[2]);
                float inter = fmaxf(d0, 0.0f) * fmaxf(d1, 0.0f) * fmaxf(d2, 0.0f);
                float va = (bx[3] - bx[0]) * (bx[4] - bx[1]) * (bx[5] - bx[2]);
                float iou = iou_term(inter, va, vb);
                if (iou > best) { best = iou; bestm = mm; }
            }
            const bool old_pos = (best >= THRESH) && (labels[b * NM + bestm] > 0);
            const bool new_pos = (labels[b * NM + m] > 0);   // overlap forced to 1.0

            const float x = scores[((size_t)b * NP + p) * 2 + 1];
            df = focal_term(x, new_pos) - focal_term(x, old_pos);
            dn = (new_pos ? 1.0f : 0.0f) - (old_pos ? 1.0f : 0.0f);

            const float* lp = &locs[((size_t)b * NP + p) * 6];
            if (new_pos) {
                const float* bx = &boxes[(b * NM + m) * 6];
                float blo[3] = {bx[0], bx[1], bx[2]}, bhi[3] = {bx[3], bx[4], bx[5]};
                dl += l1_enc(lp, blo, bhi, pc, ps);
            }
            if (old_pos) {
                const float* bx = &boxes[(b * NM + bestm) * 6];
                float blo[3] = {bx[0], bx[1], bx[2]}, bhi[3] = {bx[3], bx[4], bx[5]};
                dl -= l1_enc(lp, blo, bhi, pc, ps);
            }
        }
    }
    df = wave_sum63(df); dl = wave_sum63(dl); dn = wave_sum63(dn);
    if (lane == 63) { s_fix[wave][0] = df; s_fix[wave][1] = dl; s_fix[wave][2] = dn; }
    __syncthreads();

    // 4) finalize (single thread, fixed order)
    if (t == 0) {
        float tf = 0.0f, tl = 0.0f, tn = 0.0f;
        for (int w = 0; w < 16; ++w) {
            tf += s_red[w][0] + s_fix[w][0];
            tl += s_red[w][1] + s_fix[w][1];
            tn += s_red[w][2] + s_fix[w][2];
        }
        out[0] = tf / (float)(NB * NP);                                   // conf_loss
        out[1] = (tn > 0.5f) ? tl / fmaxf(tn * 6.0f, 1.0f) : 0.0f;        // loc_loss
    }
}

// ---------- launch (2 dispatches, no memset, no atomics) ----------

extern "C" void kernel_launch(void* const* d_in, const int* in_sizes, int n_in,
                              void* d_out, int out_size, void* d_ws, size_t ws_size,
                              hipStream_t stream) {
    const float* locs   = (const float*)d_in[0];
    const float* scores = (const float*)d_in[1];
    const float* boxes  = (const float*)d_in[2];
    const int*   labels = (const int*)d_in[3];
    const float* priors = (const float*)d_in[4];
    float* out = (float*)d_out;

    u64*    keys = (u64*)d_ws;                                        // 512 KB
    float4* part = (float4*)((char*)d_ws + (size_t)NPAIR * BPB * 8);  // 68 KB

    main_kernel<<<NBLOCKS, BLK, 0, stream>>>(locs, scores, boxes, labels, priors,
                                             keys, part);
    finalize_kernel<<<1, 1024, 0, stream>>>(locs, scores, boxes, labels, priors, keys,
                                            part, out);
}

// Round 10
// 36.317 us; speedup vs baseline: 2.8436x; 1.1817x over previous
//
#include <hip/hip_runtime.h>

#define NB 8
#define NP 131072
#define NM 16
#define THRESH 0.5f
#define BLK 256
#define PPT 2                     // priors per thread
#define PPB (BLK * PPT)           // 512 priors per block
#define BPB (NP / PPB)            // 256 match blocks per batch
#define MATCH_BLOCKS (NB * BPB)   // 2048
#define FOCAL_BLOCKS 128          // streaming focal-baseline blocks
#define NBLOCKS (MATCH_BLOCKS + FOCAL_BLOCKS)   // 2176
#define NPAIR (NB * NM)           // 128

typedef unsigned long long u64;
typedef unsigned int u32;

// ---------- DPP wave-64 reductions ----------
// row_shr 1,2,4,8 then row_bcast:15, row_bcast:31; lane 63 holds the result.
// old=0 fill is harmless for sum (adds 0) and max of non-negatives.

template <int CTRL>
__device__ __forceinline__ float dppmv(float x) {
    return __int_as_float(__builtin_amdgcn_update_dpp(
        0, __float_as_int(x), CTRL, 0xf, 0xf, false));
}

__device__ __forceinline__ float wave_max63(float x) {   // x >= 0 required
    x = fmaxf(x, dppmv<0x111>(x));
    x = fmaxf(x, dppmv<0x112>(x));
    x = fmaxf(x, dppmv<0x114>(x));
    x = fmaxf(x, dppmv<0x118>(x));
    x = fmaxf(x, dppmv<0x142>(x));
    x = fmaxf(x, dppmv<0x143>(x));
    return x;
}

__device__ __forceinline__ float wave_sum63(float x) {
    x += dppmv<0x111>(x);
    x += dppmv<0x112>(x);
    x += dppmv<0x114>(x);
    x += dppmv<0x118>(x);
    x += dppmv<0x142>(x);
    x += dppmv<0x143>(x);
    return x;
}

__device__ __forceinline__ float bcast63(float x) {
    return __int_as_float(__builtin_amdgcn_readlane(__float_as_int(x), 63));
}

// ---------- shared math (identical formulas everywhere) ----------

__device__ __forceinline__ float iou_term(float inter, float va, float vb) {
    return (inter > 0.0f) ? inter * __builtin_amdgcn_rcpf(va + vb - inter) : 0.0f;
}

__device__ __forceinline__ float focal_term(float x, bool pos) {
    float t = __expf(-fabsf(x));                 // e^{-|x|}
    float r = __builtin_amdgcn_rcpf(1.0f + t);   // 1/(1+t)
    float L = __logf(1.0f + t);                  // log1p(e^{-|x|})
    float ce = (pos ? fmaxf(-x, 0.0f) : fmaxf(x, 0.0f)) + L;   // softplus
    float omp = (pos == (x >= 0.0f)) ? t * r : r;              // 1 - pt
    float w = pos ? 0.25f : 0.75f;
    return w * omp * omp * ce;
}

__device__ __forceinline__ float l1_enc(const float* lp,
                                        const float blo[3], const float bhi[3],
                                        const float pc[3], const float ps[3]) {
    float s = 0.0f;
#pragma unroll
    for (int k = 0; k < 3; ++k) {
        float gc = (blo[k] + bhi[k]) / 2.0f;
        float gs = bhi[k] - blo[k];
        float e  = (gc - pc[k]) / (ps[k] / 10.0f);
        float e2 = __logf(gs / ps[k]) * 5.0f;
        s += fabsf(lp[k]     - e);
        s += fabsf(lp[3 + k] - e2);
    }
    return s;
}

__device__ __forceinline__ u32 decode_p(u64 k) { return ~(u32)(k & 0xFFFFFFFFull); }

// ---------- kernel 1: match role (PPT=2, packed regs) + focal-baseline role ----------

__global__ __launch_bounds__(BLK) void main_kernel(
        const float* __restrict__ locs, const float* __restrict__ scores,
        const float* __restrict__ boxes, const int* __restrict__ labels,
        const float* __restrict__ priors,
        u64* __restrict__ keys_out,              // [NPAIR][BPB], fully written
        float4* __restrict__ part) {             // [NBLOCKS]
    __shared__ float4 s_box[NM][2];              // {lo0,lo1,lo2,hi0} {hi1,hi2,va,lab}
    __shared__ u64    s_wkey[4][NM];
    __shared__ float  s_wred[4][3];

    const int tid  = threadIdx.x;
    const int bid  = blockIdx.x;
    const int lane = tid & 63, wave = tid >> 6;

    // ===== focal-baseline role: sum focal(x, 0) over all (b,p) =====
    if (bid >= MATCH_BLOCKS) {
        const int fblk = bid - MATCH_BLOCKS;
        const float4* sc4 = reinterpret_cast<const float4*>(scores);
        // scores: 2M floats = 524288 float4; 4096 per block, 16 per thread
        float f = 0.0f;
#pragma unroll
        for (int i = 0; i < 16; ++i) {
            float4 v = sc4[(size_t)fblk * 4096 + i * BLK + tid];
            f += focal_term(v.y, false) + focal_term(v.w, false);
        }
        f = wave_sum63(f);
        if (lane == 63) s_wred[wave][0] = f;
        __syncthreads();
        if (tid == 0)
            part[bid] = make_float4(s_wred[0][0] + s_wred[1][0] +
                                    s_wred[2][0] + s_wred[3][0], 0.0f, 0.0f, 0.0f);
        return;
    }

    // ===== match role: two priors per thread =====
    const int b    = bid >> 8;                   // bid / BPB (BPB = 256)
    const int xblk = bid & (BPB - 1);
    const int p0   = (xblk << 9) + 2 * tid;      // even
    const int pbase = (xblk << 9) + (wave << 7); // p of lane 0, slot 0

    if (tid < NM) {
        const float* bx = &boxes[(b * NM + tid) * 6];
        float l0 = bx[0], l1 = bx[1], l2 = bx[2];
        float h0 = bx[3], h1 = bx[4], h2 = bx[5];
        s_box[tid][0] = make_float4(l0, l1, l2, h0);
        float va = (h0 - l0) * (h1 - l1) * (h2 - l2);
        s_box[tid][1] = make_float4(h1, h2, va, __int_as_float(labels[b * NM + tid]));
    }
    __syncthreads();

    // two priors: 3 aligned float4 loads; mirror reference op order
    const float4* pr4 = reinterpret_cast<const float4*>(priors);
    const size_t f4b = (size_t)(p0 / 2) * 3;
    float pl0[3], ph0[3], pl1[3], ph1[3];
    float vb0, vb1;
    {
        float4 q0 = pr4[f4b + 0], q1 = pr4[f4b + 1], q2 = pr4[f4b + 2];
        const float pc0[3] = {q0.x, q0.y, q0.z}, ps0[3] = {q0.w, q1.x, q1.y};
        const float pc1[3] = {q1.z, q1.w, q2.x}, ps1[3] = {q2.y, q2.z, q2.w};
#pragma unroll
        for (int k = 0; k < 3; ++k) {
            pl0[k] = pc0[k] - ps0[k] / 2.0f; ph0[k] = pc0[k] + ps0[k] / 2.0f;
            pl1[k] = pc1[k] - ps1[k] / 2.0f; ph1[k] = pc1[k] + ps1[k] / 2.0f;
        }
        vb0 = (ph0[0] - pl0[0]) * (ph0[1] - pl0[1]) * (ph0[2] - pl0[2]);
        vb1 = (ph1[0] - pl1[0]) * (ph1[1] - pl1[1]) * (ph1[2] - pl1[2]);
    }

    // phase 1: per-m in-lane winner; 1-bit slot pack instead of cp[16]
    float ci[NM];
    u32 spack = 0u;                              // bit m = winning slot for m
    float best0 = -1.0f, best1 = -1.0f;
    int bm0 = 0, bm1 = 0;
#pragma unroll
    for (int m = 0; m < NM; ++m) {
        float4 A = s_box[m][0], B4 = s_box[m][1];
        float d0 = fminf(A.w,  ph0[0]) - fmaxf(A.x, pl0[0]);
        float d1 = fminf(B4.x, ph0[1]) - fmaxf(A.y, pl0[1]);
        float d2 = fminf(B4.y, ph0[2]) - fmaxf(A.z, pl0[2]);
        float i0 = iou_term(fmaxf(d0, 0.0f) * fmaxf(d1, 0.0f) * fmaxf(d2, 0.0f),
                            B4.z, vb0);
        d0 = fminf(A.w,  ph1[0]) - fmaxf(A.x, pl1[0]);
        d1 = fminf(B4.x, ph1[1]) - fmaxf(A.y, pl1[1]);
        d2 = fminf(B4.y, ph1[2]) - fmaxf(A.z, pl1[2]);
        float i1 = iou_term(fmaxf(d0, 0.0f) * fmaxf(d1, 0.0f) * fmaxf(d2, 0.0f),
                            B4.z, vb1);
        if (i0 > best0) { best0 = i0; bm0 = m; }     // strict > = first max
        if (i1 > best1) { best1 = i1; bm1 = m; }
        const bool s1 = (i1 > i0);                   // ascending p, lowest p on tie
        ci[m] = s1 ? i1 : i0;
        spack |= (s1 ? 1u : 0u) << m;
    }

    // phase 2: 16 independent wave-max chains; slot recovered via readlane
#pragma unroll
    for (int m = 0; m < NM; ++m) {
        float wm = bcast63(wave_max63(ci[m]));
        u64 eq = __ballot(ci[m] == wm);
        int ls = __ffsll(eq) - 1;                    // lowest lane = lowest p
        u32 sp = (u32)__builtin_amdgcn_readlane((int)spack, ls);
        u32 wp = (u32)(pbase + 2 * ls) + ((sp >> m) & 1u);
        if (lane == 0)
            s_wkey[wave][m] = ((u64)__float_as_uint(wm) << 32) | (u32)~wp;
    }

    // epilogue: delta-focal + loc, only under the rare positive mask
    float f = 0.0f, l = 0.0f, n = 0.0f;
    {
        float4 Bb = s_box[bm0][1];
        if ((best0 >= THRESH) && (__float_as_int(Bb.w) > 0)) {
            const float x = scores[((size_t)b * NP + p0) * 2 + 1];
            f += focal_term(x, true) - focal_term(x, false);
            float4 Ab = s_box[bm0][0];
            float blo[3] = {Ab.x, Ab.y, Ab.z}, bhi[3] = {Ab.w, Bb.x, Bb.y};
            float pc[3], ps[3];
#pragma unroll
            for (int k = 0; k < 3; ++k) { pc[k] = priors[p0 * 6 + k]; ps[k] = priors[p0 * 6 + 3 + k]; }
            l += l1_enc(&locs[((size_t)b * NP + p0) * 6], blo, bhi, pc, ps);
            n += 1.0f;
        }
        Bb = s_box[bm1][1];
        if ((best1 >= THRESH) && (__float_as_int(Bb.w) > 0)) {
            const int p1 = p0 + 1;
            const float x = scores[((size_t)b * NP + p1) * 2 + 1];
            f += focal_term(x, true) - focal_term(x, false);
            float4 Ab = s_box[bm1][0];
            float blo[3] = {Ab.x, Ab.y, Ab.z}, bhi[3] = {Ab.w, Bb.x, Bb.y};
            float pc[3], ps[3];
#pragma unroll
            for (int k = 0; k < 3; ++k) { pc[k] = priors[p1 * 6 + k]; ps[k] = priors[p1 * 6 + 3 + k]; }
            l += l1_enc(&locs[((size_t)b * NP + p1) * 6], blo, bhi, pc, ps);
            n += 1.0f;
        }
    }

    f = wave_sum63(f); l = wave_sum63(l); n = wave_sum63(n);
    if (lane == 63) { s_wred[wave][0] = f; s_wred[wave][1] = l; s_wred[wave][2] = n; }
    __syncthreads();

    if (tid < NM) {
        u64 k = s_wkey[0][tid];
#pragma unroll
        for (int w = 1; w < 4; ++w) k = (s_wkey[w][tid] > k) ? s_wkey[w][tid] : k;
        keys_out[(size_t)(b * NM + tid) * BPB + xblk] = k;
    }
    if (tid == 0) {
        part[bid] = make_float4(s_wred[0][0] + s_wred[1][0] + s_wred[2][0] + s_wred[3][0],
                                s_wred[0][1] + s_wred[1][1] + s_wred[2][1] + s_wred[3][1],
                                s_wred[0][2] + s_wred[1][2] + s_wred[2][2] + s_wred[3][2],
                                0.0f);
    }
}

// ---------- kernel 2: key reduce + partial reduce + override fixups + finalize ----------

__global__ __launch_bounds__(1024) void finalize_kernel(
        const float* __restrict__ locs, const float* __restrict__ scores,
        const float* __restrict__ boxes, const int* __restrict__ labels,
        const float* __restrict__ priors, const u64* __restrict__ keys_in,
        const float4* __restrict__ part, float* __restrict__ out) {
    __shared__ u64   s_key[NPAIR];
    __shared__ float s_red[16][3];
    __shared__ float s_fix[16][3];
    const int t = threadIdx.x, lane = t & 63, wave = t >> 6;   // 16 waves

    // 1) reduce per-block partials (match f/l/n + focal baselines)
    float f = 0.0f, l = 0.0f, n = 0.0f;
    for (int i = t; i < NBLOCKS; i += 1024) {
        float4 v = part[i]; f += v.x; l += v.y; n += v.z;
    }
    f = wave_sum63(f); l = wave_sum63(l); n = wave_sum63(n);
    if (lane == 63) { s_red[wave][0] = f; s_red[wave][1] = l; s_red[wave][2] = n; }

    // 2) global key max per (b,m): one wave per 8 pairs
#pragma unroll
    for (int i = 0; i < 8; ++i) {
        const int pair = wave * 8 + i;
        const u64* kp = keys_in + (size_t)pair * BPB;
        u64 k = 0;
#pragma unroll
        for (int j = 0; j < BPB / 64; ++j) {     // 4 coalesced loads per lane
            u64 v = kp[j * 64 + lane];
            k = (v > k) ? v : k;
        }
#pragma unroll
        for (int off = 32; off > 0; off >>= 1) {
            u64 o = __shfl_down(k, off);
            k = (o > k) ? o : k;
        }
        if (lane == 0) s_key[pair] = k;
    }
    __syncthreads();

    // 3) per-(b,m) override fixup (delta form matches the split-focal sum)
    float df = 0.0f, dl = 0.0f, dn = 0.0f;
    if (t < NPAIR) {
        const int b = t / NM, m = t % NM;
        const u32 pstar = decode_p(s_key[t]);
        bool skip = false;                        // duplicate prior: last m wins
        for (int mm = m + 1; mm < NM; ++mm)
            skip |= (decode_p(s_key[b * NM + mm]) == pstar);
        if (!skip) {
            const int p = (int)pstar;
            float pc[3], ps[3], pl[3], ph[3];
#pragma unroll
            for (int k = 0; k < 3; ++k) { pc[k] = priors[p * 6 + k]; ps[k] = priors[p * 6 + 3 + k]; }
#pragma unroll
            for (int k = 0; k < 3; ++k) { pl[k] = pc[k] - ps[k] / 2.0f; ph[k] = pc[k] + ps[k] / 2.0f; }
            const float vb = (ph[0] - pl[0]) * (ph[1] - pl[1]) * (ph[2] - pl[2]);

            // recompute this prior's original best match (bit-identical math)
            float best = -1.0f; int bestm = 0;
            for (int mm = 0; mm < NM; ++mm) {
                const float* bx = &boxes[(b * NM + mm) * 6];
                float d0 = fminf(bx[3], ph[0]) - fmaxf(bx[0], pl[0]);
                float d1 = fminf(bx[4], ph[1]) - fmaxf(bx[1], pl[1]);
                float d2 = fminf(bx[5], ph[2]) - fmaxf(bx[2], pl[2]);
                float inter = fmaxf(d0, 0.0f) * fmaxf(d1, 0.0f) * fmaxf(d2, 0.0f);
                float va = (bx[3] - bx[0]) * (bx[4] - bx[1]) * (bx[5] - bx[2]);
                float iou = iou_term(inter, va, vb);
                if (iou > best) { best = iou; bestm = mm; }
            }
            const bool old_pos = (best >= THRESH) && (labels[b * NM + bestm] > 0);
            const bool new_pos = (labels[b * NM + m] > 0);   // overlap forced to 1.0

            const float x = scores[((size_t)b * NP + p) * 2 + 1];
            df = focal_term(x, new_pos) - focal_term(x, old_pos);
            dn = (new_pos ? 1.0f : 0.0f) - (old_pos ? 1.0f : 0.0f);

            const float* lp = &locs[((size_t)b * NP + p) * 6];
            if (new_pos) {
                const float* bx = &boxes[(b * NM + m) * 6];
                float blo[3] = {bx[0], bx[1], bx[2]}, bhi[3] = {bx[3], bx[4], bx[5]};
                dl += l1_enc(lp, blo, bhi, pc, ps);
            }
            if (old_pos) {
                const float* bx = &boxes[(b * NM + bestm) * 6];
                float blo[3] = {bx[0], bx[1], bx[2]}, bhi[3] = {bx[3], bx[4], bx[5]};
                dl -= l1_enc(lp, blo, bhi, pc, ps);
            }
        }
    }
    df = wave_sum63(df); dl = wave_sum63(dl); dn = wave_sum63(dn);
    if (lane == 63) { s_fix[wave][0] = df; s_fix[wave][1] = dl; s_fix[wave][2] = dn; }
    __syncthreads();

    // 4) finalize (single thread, fixed order)
    if (t == 0) {
        float tf = 0.0f, tl = 0.0f, tn = 0.0f;
        for (int w = 0; w < 16; ++w) {
            tf += s_red[w][0] + s_fix[w][0];
            tl += s_red[w][1] + s_fix[w][1];
            tn += s_red[w][2] + s_fix[w][2];
        }
        out[0] = tf / (float)(NB * NP);                                   // conf_loss
        out[1] = (tn > 0.5f) ? tl / fmaxf(tn * 6.0f, 1.0f) : 0.0f;        // loc_loss
    }
}

// ---------- launch (2 dispatches, no memset, no atomics) ----------

extern "C" void kernel_launch(void* const* d_in, const int* in_sizes, int n_in,
                              void* d_out, int out_size, void* d_ws, size_t ws_size,
                              hipStream_t stream) {
    const float* locs   = (const float*)d_in[0];
    const float* scores = (const float*)d_in[1];
    const float* boxes  = (const float*)d_in[2];
    const int*   labels = (const int*)d_in[3];
    const float* priors = (const float*)d_in[4];
    float* out = (float*)d_out;

    u64*    keys = (u64*)d_ws;                                        // 256 KB
    float4* part = (float4*)((char*)d_ws + (size_t)NPAIR * BPB * 8);  // 35 KB

    main_kernel<<<NBLOCKS, BLK, 0, stream>>>(locs, scores, boxes, labels, priors,
                                             keys, part);
    finalize_kernel<<<1, 1024, 0, stream>>>(locs, scores, boxes, labels, priors, keys,
                                            part, out);
}